// Round 1
// baseline (548.317 us; speedup 1.0000x reference)
//
#include <hip/hip_runtime.h>
#include <math.h>

// Problem constants
//   B=64, M=128, J=512, T=513, E=256, H=16, D=16
//   out: (B, M*T) = (64, 65664) fp32 probabilities

#define LDT 68   // LDS leading dim: keeps float4 (16B) alignment, <=2-way bank aliasing

// ---------------------------------------------------------------------------
// Tiled fp32 GEMM: C[rows x 256] = A(rows x 256) @ W(256 x 256) (+ bias)
// 64x64 tile, 256 threads, 4x4 accumulators per thread.
// MODE 0: A is a direct row-major pointer.
// MODE 1: A is the "virtual jobs" matrix: row r -> (b=r/513, t=r%513);
//         t==0 -> skip_emb row, else encoded_jobs[b][t-1].
// ---------------------------------------------------------------------------
template<int MODE>
__global__ __launch_bounds__(256) void gemm64(
    const float* __restrict__ A, const float* __restrict__ jobs,
    const float* __restrict__ skip, const float* __restrict__ W,
    const float* __restrict__ bias, float* __restrict__ C)
{
  __shared__ float As[16 * LDT];
  __shared__ float Bs[16 * LDT];
  const int tid = threadIdx.x;
  const int bx = blockIdx.x, by = blockIdx.y;

  // A-tile load mapping: thread -> (row m_l, 4 consecutive k)
  const int m_l = tid >> 2;
  const int kk4 = (tid & 3) << 2;
  const int row = by * 64 + m_l;
  const float* arow;
  if (MODE == 0) {
    arow = A + ((size_t)row << 8);
  } else {
    const int bb = row / 513;
    const int t  = row - bb * 513;
    arow = (t == 0) ? skip : (jobs + ((size_t)(bb * 512 + t - 1) << 8));
  }

  // B-tile load mapping: thread -> (k row nb, 4 consecutive n)
  const int nb = tid >> 4;
  const int n4 = (tid & 15) << 2;

  const int tr = tid >> 4, tc = tid & 15;
  float acc[4][4] = {};

  for (int k0 = 0; k0 < 256; k0 += 16) {
    const float4 av = *(const float4*)(arow + k0 + kk4);
    const float4 bv = *(const float4*)(W + ((size_t)(k0 + nb) << 8) + bx * 64 + n4);
    __syncthreads();
    As[(kk4 + 0) * LDT + m_l] = av.x;
    As[(kk4 + 1) * LDT + m_l] = av.y;
    As[(kk4 + 2) * LDT + m_l] = av.z;
    As[(kk4 + 3) * LDT + m_l] = av.w;
    *(float4*)&Bs[nb * LDT + n4] = bv;
    __syncthreads();
    #pragma unroll
    for (int k = 0; k < 16; ++k) {
      const float4 a = *(const float4*)&As[k * LDT + (tr << 2)];
      const float4 b = *(const float4*)&Bs[k * LDT + (tc << 2)];
      acc[0][0] = fmaf(a.x, b.x, acc[0][0]); acc[0][1] = fmaf(a.x, b.y, acc[0][1]);
      acc[0][2] = fmaf(a.x, b.z, acc[0][2]); acc[0][3] = fmaf(a.x, b.w, acc[0][3]);
      acc[1][0] = fmaf(a.y, b.x, acc[1][0]); acc[1][1] = fmaf(a.y, b.y, acc[1][1]);
      acc[1][2] = fmaf(a.y, b.z, acc[1][2]); acc[1][3] = fmaf(a.y, b.w, acc[1][3]);
      acc[2][0] = fmaf(a.z, b.x, acc[2][0]); acc[2][1] = fmaf(a.z, b.y, acc[2][1]);
      acc[2][2] = fmaf(a.z, b.z, acc[2][2]); acc[2][3] = fmaf(a.z, b.w, acc[2][3]);
      acc[3][0] = fmaf(a.w, b.x, acc[3][0]); acc[3][1] = fmaf(a.w, b.y, acc[3][1]);
      acc[3][2] = fmaf(a.w, b.z, acc[3][2]); acc[3][3] = fmaf(a.w, b.w, acc[3][3]);
    }
  }

  const int col0 = bx * 64 + (tc << 2);
  float4 bs4 = make_float4(0.f, 0.f, 0.f, 0.f);
  if (bias) bs4 = *(const float4*)(bias + col0);
  #pragma unroll
  for (int i = 0; i < 4; ++i) {
    float4 o;
    o.x = acc[i][0] + bs4.x; o.y = acc[i][1] + bs4.y;
    o.z = acc[i][2] + bs4.z; o.w = acc[i][3] + bs4.w;
    *(float4*)(C + ((size_t)(by * 64 + (tr << 2) + i) << 8) + col0) = o;
  }
}

// ---------------------------------------------------------------------------
// Flash-style attention: one block per (h, b), one thread per m (128 threads).
// K/V tiles of 64 rows staged in LDS -> each K/V element read once globally.
// Writes out_concat (B, M, H*D) so the Wc projection is a plain GEMM.
// ---------------------------------------------------------------------------
__global__ __launch_bounds__(128) void attn_flash(
    const float* __restrict__ Q, const float* __restrict__ K,
    const float* __restrict__ V, float* __restrict__ OC)
{
  const int h = blockIdx.x, b = blockIdx.y;
  const int tid = threadIdx.x;                 // m index
  __shared__ float Ks[64 * 16];
  __shared__ float Vs[64 * 16];

  float q[16], o[16] = {};
  {
    const float* qp = Q + ((size_t)(b * 128 + tid) << 8) + h * 16;
    #pragma unroll
    for (int i = 0; i < 16; i += 4) {
      const float4 v = *(const float4*)(qp + i);
      q[i] = v.x; q[i+1] = v.y; q[i+2] = v.z; q[i+3] = v.w;
    }
  }

  float mx = -3.4e38f, l = 0.f;
  const int r = tid >> 1;            // tile row 0..63
  const int c = (tid & 1) << 3;      // 0 or 8

  for (int t0 = 0; t0 < 513; t0 += 64) {
    const int nt = (513 - t0 < 64) ? (513 - t0) : 64;
    __syncthreads();
    if (r < nt) {
      const size_t off = ((size_t)(b * 513 + t0 + r) << 8) + h * 16 + c;
      const float4 k0v = *(const float4*)(K + off);
      const float4 k1v = *(const float4*)(K + off + 4);
      const float4 v0v = *(const float4*)(V + off);
      const float4 v1v = *(const float4*)(V + off + 4);
      *(float4*)&Ks[r * 16 + c]     = k0v;
      *(float4*)&Ks[r * 16 + c + 4] = k1v;
      *(float4*)&Vs[r * 16 + c]     = v0v;
      *(float4*)&Vs[r * 16 + c + 4] = v1v;
    }
    __syncthreads();
    for (int t = 0; t < nt; ++t) {
      float s = 0.f;
      #pragma unroll
      for (int d = 0; d < 16; ++d) s = fmaf(q[d], Ks[t * 16 + d], s);
      s *= 0.25f;                                   // / SQRT_QKV
      const float mnew  = fmaxf(mx, s);
      const float scale = expf(mx - mnew);
      const float e     = expf(s - mnew);
      l = l * scale + e;
      #pragma unroll
      for (int d = 0; d < 16; ++d) o[d] = fmaf(e, Vs[t * 16 + d], o[d] * scale);
      mx = mnew;
    }
  }

  const float inv = 1.f / l;
  float* op = OC + ((size_t)(b * 128 + tid) << 8) + h * 16;
  #pragma unroll
  for (int i = 0; i < 16; i += 4) {
    float4 v;
    v.x = o[i] * inv; v.y = o[i+1] * inv; v.z = o[i+2] * inv; v.w = o[i+3] * inv;
    *(float4*)(op + i) = v;
  }
}

// ---------------------------------------------------------------------------
// Logits: per-b GEMM  C(128 x 513) = MH(128 x 256) @ jobs(b)^T(256 x 513)
// fused epilogue: 10*tanh(x/16) + mask. grid (9 t-tiles, 2 m-tiles, 64 b).
// ---------------------------------------------------------------------------
__global__ __launch_bounds__(256) void logits_gemm(
    const float* __restrict__ MH, const float* __restrict__ jobs,
    const float* __restrict__ skip, const float* __restrict__ mask,
    float* __restrict__ out)
{
  __shared__ float As[16 * LDT];
  __shared__ float Bs[16 * LDT];
  const int tid = threadIdx.x;
  const int b = blockIdx.z;

  const int m_l = tid >> 2;
  const int kk4 = (tid & 3) << 2;
  const float* arow = MH + ((size_t)(b * 128 + blockIdx.y * 64 + m_l) << 8);

  const int t_g = blockIdx.x * 64 + m_l;
  const float* brow = nullptr;
  if (t_g < 513)
    brow = (t_g == 0) ? skip : (jobs + ((size_t)(b * 512 + t_g - 1) << 8));

  const int tr = tid >> 4, tc = tid & 15;
  float acc[4][4] = {};

  for (int k0 = 0; k0 < 256; k0 += 16) {
    const float4 av = *(const float4*)(arow + k0 + kk4);
    float4 bv = make_float4(0.f, 0.f, 0.f, 0.f);
    if (brow) bv = *(const float4*)(brow + k0 + kk4);
    __syncthreads();
    As[(kk4 + 0) * LDT + m_l] = av.x;
    As[(kk4 + 1) * LDT + m_l] = av.y;
    As[(kk4 + 2) * LDT + m_l] = av.z;
    As[(kk4 + 3) * LDT + m_l] = av.w;
    Bs[(kk4 + 0) * LDT + m_l] = bv.x;
    Bs[(kk4 + 1) * LDT + m_l] = bv.y;
    Bs[(kk4 + 2) * LDT + m_l] = bv.z;
    Bs[(kk4 + 3) * LDT + m_l] = bv.w;
    __syncthreads();
    #pragma unroll
    for (int k = 0; k < 16; ++k) {
      const float4 a = *(const float4*)&As[k * LDT + (tr << 2)];
      const float4 b4 = *(const float4*)&Bs[k * LDT + (tc << 2)];
      acc[0][0] = fmaf(a.x, b4.x, acc[0][0]); acc[0][1] = fmaf(a.x, b4.y, acc[0][1]);
      acc[0][2] = fmaf(a.x, b4.z, acc[0][2]); acc[0][3] = fmaf(a.x, b4.w, acc[0][3]);
      acc[1][0] = fmaf(a.y, b4.x, acc[1][0]); acc[1][1] = fmaf(a.y, b4.y, acc[1][1]);
      acc[1][2] = fmaf(a.y, b4.z, acc[1][2]); acc[1][3] = fmaf(a.y, b4.w, acc[1][3]);
      acc[2][0] = fmaf(a.z, b4.x, acc[2][0]); acc[2][1] = fmaf(a.z, b4.y, acc[2][1]);
      acc[2][2] = fmaf(a.z, b4.z, acc[2][2]); acc[2][3] = fmaf(a.z, b4.w, acc[2][3]);
      acc[3][0] = fmaf(a.w, b4.x, acc[3][0]); acc[3][1] = fmaf(a.w, b4.y, acc[3][1]);
      acc[3][2] = fmaf(a.w, b4.z, acc[3][2]); acc[3][3] = fmaf(a.w, b4.w, acc[3][3]);
    }
  }

  #pragma unroll
  for (int i = 0; i < 4; ++i) {
    const int mm = blockIdx.y * 64 + (tr << 2) + i;
    #pragma unroll
    for (int j = 0; j < 4; ++j) {
      const int tt = blockIdx.x * 64 + (tc << 2) + j;
      if (tt < 513) {
        const float v = 10.f * tanhf(acc[i][j] * 0.0625f)
                      + mask[((size_t)(b * 128 + mm)) * 513 + tt];
        out[(size_t)b * 65664 + (size_t)mm * 513 + tt] = v;
      }
    }
  }
}

// ---------------------------------------------------------------------------
// Batch-wide softmax over M*T = 65664 elements per b, in place on d_out.
// ---------------------------------------------------------------------------
__global__ __launch_bounds__(1024) void softmax_batch(float* __restrict__ out)
{
  const int b = blockIdx.x;
  float* p = out + (size_t)b * 65664;
  const int tid = threadIdx.x, lane = tid & 63, w = tid >> 6;
  __shared__ float red[16];

  float mx = -3.4e38f;
  for (int i = tid; i < 65664; i += 1024) mx = fmaxf(mx, p[i]);
  #pragma unroll
  for (int off = 32; off; off >>= 1) mx = fmaxf(mx, __shfl_xor(mx, off));
  if (lane == 0) red[w] = mx;
  __syncthreads();
  if (tid < 16) {
    float v = red[tid];
    #pragma unroll
    for (int off = 8; off; off >>= 1) v = fmaxf(v, __shfl_xor(v, off));
    if (tid == 0) red[0] = v;
  }
  __syncthreads();
  mx = red[0];
  __syncthreads();   // everyone has read red[0] before it is reused

  float s = 0.f;
  for (int i = tid; i < 65664; i += 1024) s += expf(p[i] - mx);
  #pragma unroll
  for (int off = 32; off; off >>= 1) s += __shfl_xor(s, off);
  if (lane == 0) red[w] = s;
  __syncthreads();
  if (tid < 16) {
    float v = red[tid];
    #pragma unroll
    for (int off = 8; off; off >>= 1) v += __shfl_xor(v, off);
    if (tid == 0) red[0] = v;
  }
  __syncthreads();
  const float inv = 1.f / red[0];
  for (int i = tid; i < 65664; i += 1024) p[i] = expf(p[i] - mx) * inv;
}

// ---------------------------------------------------------------------------
extern "C" void kernel_launch(void* const* d_in, const int* in_sizes, int n_in,
                              void* d_out, int out_size, void* d_ws, size_t ws_size,
                              hipStream_t stream)
{
  const float* machine = (const float*)d_in[0];  // (64,128,256)
  const float* jobs    = (const float*)d_in[1];  // (64,512,256)
  const float* mask    = (const float*)d_in[2];  // (64,128,513)
  const float* Wq      = (const float*)d_in[3];  // (256,256)
  const float* Wk      = (const float*)d_in[4];
  const float* Wv      = (const float*)d_in[5];
  const float* Wc      = (const float*)d_in[6];
  const float* bc      = (const float*)d_in[7];  // (256,)
  const float* skip    = (const float*)d_in[8];  // (256,)

  float* ws  = (float*)d_ws;
  float* Qw  = ws;                    // 8192*256      = 2,097,152 f
  float* Kw  = ws + 2097152;          // 32832*256     = 8,404,992 f
  float* Vw  = ws + 10502144;         // 8,404,992 f
  float* OC  = ws + 18907136;         // 2,097,152 f
  float* MH  = ws + 21004288;         // 2,097,152 f  (total ~92.4 MB)
  float* out = (float*)d_out;         // (64, 65664)

  // Q = machine @ Wq3
  gemm64<0><<<dim3(4, 128), 256, 0, stream>>>(machine, nullptr, nullptr, Wq, nullptr, Qw);
  // K = jobs @ Wk ; V = jobs @ Wv   (virtual jobs: row 0 = skip_emb)
  gemm64<1><<<dim3(4, 513), 256, 0, stream>>>(nullptr, jobs, skip, Wk, nullptr, Kw);
  gemm64<1><<<dim3(4, 513), 256, 0, stream>>>(nullptr, jobs, skip, Wv, nullptr, Vw);
  // attention -> out_concat
  attn_flash<<<dim3(16, 64), 128, 0, stream>>>(Qw, Kw, Vw, OC);
  // mh = out_concat @ Wc + bc
  gemm64<0><<<dim3(4, 128), 256, 0, stream>>>(OC, nullptr, nullptr, Wc, bc, MH);
  // logits = 10*tanh((mh @ jobs^T)/16) + mask
  logits_gemm<<<dim3(9, 2, 64), 256, 0, stream>>>(MH, jobs, skip, mask, out);
  // probs = softmax over (M*T) per batch
  softmax_batch<<<64, 1024, 0, stream>>>(out);
}

// Round 3
// 458.177 us; speedup vs baseline: 1.1967x; 1.1967x over previous
//
#include <hip/hip_runtime.h>
#include <math.h>

// B=64, M=128, J=512, T=513, E=256, H=16, D=16; out (64, 65664) fp32.

#define LDT 68    // 64-row A-tile LDS leading dim
#define LDB 132   // 128-col B-tile LDS leading dim

// ---------------------------------------------------------------------------
// Wide tiled fp32 GEMM: C[rows x 256] = A(rows x 256) @ W(256 x 256) (+bias)
// 64x128 tile, 256 threads, 4x8 acc. MODE 0: direct A. MODE 1: virtual jobs
// (row r -> b=r/513,t=r%513; t==0 -> skip row). DUAL 1: cols 0..255 -> W1/C1,
// 256..511 -> W2/C2 (whole 128-col tile is on one side).
// ---------------------------------------------------------------------------
template<int MODE, int DUAL>
__global__ __launch_bounds__(256) void gemm_wide(
    const float* __restrict__ A, const float* __restrict__ jobs,
    const float* __restrict__ skip, const float* __restrict__ W1,
    const float* __restrict__ W2, const float* __restrict__ bias,
    float* __restrict__ C1, float* __restrict__ C2)
{
  __shared__ float As[16 * LDT];
  __shared__ float Bs[16 * LDB];
  const int tid = threadIdx.x;
  const int bx = blockIdx.x, by = blockIdx.y;

  const float* W; float* C; int col0;
  if (DUAL) {
    const int g = bx * 128;
    if (g >= 256) { W = W2; C = C2; col0 = g - 256; }
    else          { W = W1; C = C1; col0 = g; }
  } else { W = W1; C = C1; col0 = bx * 128; }

  // A staging map: row, 4 consecutive k
  const int a_row = tid >> 2;
  const int a_k4  = (tid & 3) << 2;
  const int row = by * 64 + a_row;
  const float* arow;
  if (MODE == 0) {
    arow = A + ((size_t)row << 8);
  } else {
    const int bb = row / 513;
    const int t  = row - bb * 513;
    arow = (t == 0) ? skip : (jobs + ((size_t)(bb * 512 + t - 1) << 8));
  }

  // B staging map: k row, 8 consecutive cols
  const int b_k  = tid >> 4;
  const int b_c8 = (tid & 15) << 3;

  const int tr = tid >> 4, tc = tid & 15;
  float acc[4][8] = {};

  for (int k0 = 0; k0 < 256; k0 += 16) {
    const float4 av  = *(const float4*)(arow + k0 + a_k4);
    const float4 bv0 = *(const float4*)(W + ((size_t)(k0 + b_k) << 8) + col0 + b_c8);
    const float4 bv1 = *(const float4*)(W + ((size_t)(k0 + b_k) << 8) + col0 + b_c8 + 4);
    __syncthreads();
    As[(a_k4 + 0) * LDT + a_row] = av.x;
    As[(a_k4 + 1) * LDT + a_row] = av.y;
    As[(a_k4 + 2) * LDT + a_row] = av.z;
    As[(a_k4 + 3) * LDT + a_row] = av.w;
    *(float4*)&Bs[b_k * LDB + b_c8]     = bv0;
    *(float4*)&Bs[b_k * LDB + b_c8 + 4] = bv1;
    __syncthreads();
    #pragma unroll
    for (int k = 0; k < 16; ++k) {
      const float4 a  = *(const float4*)&As[k * LDT + (tr << 2)];
      const float4 b0 = *(const float4*)&Bs[k * LDB + (tc << 3)];
      const float4 b1 = *(const float4*)&Bs[k * LDB + (tc << 3) + 4];
      const float aa[4] = {a.x, a.y, a.z, a.w};
      #pragma unroll
      for (int i = 0; i < 4; ++i) {
        acc[i][0] = fmaf(aa[i], b0.x, acc[i][0]);
        acc[i][1] = fmaf(aa[i], b0.y, acc[i][1]);
        acc[i][2] = fmaf(aa[i], b0.z, acc[i][2]);
        acc[i][3] = fmaf(aa[i], b0.w, acc[i][3]);
        acc[i][4] = fmaf(aa[i], b1.x, acc[i][4]);
        acc[i][5] = fmaf(aa[i], b1.y, acc[i][5]);
        acc[i][6] = fmaf(aa[i], b1.z, acc[i][6]);
        acc[i][7] = fmaf(aa[i], b1.w, acc[i][7]);
      }
    }
  }

  const int oc = col0 + (tc << 3);
  float4 bsa = make_float4(0.f,0.f,0.f,0.f), bsb = make_float4(0.f,0.f,0.f,0.f);
  if (bias) { bsa = *(const float4*)(bias + oc); bsb = *(const float4*)(bias + oc + 4); }
  #pragma unroll
  for (int i = 0; i < 4; ++i) {
    float* crow = C + ((size_t)(by * 64 + (tr << 2) + i) << 8) + oc;
    float4 o0, o1;
    o0.x = acc[i][0]+bsa.x; o0.y = acc[i][1]+bsa.y; o0.z = acc[i][2]+bsa.z; o0.w = acc[i][3]+bsa.w;
    o1.x = acc[i][4]+bsb.x; o1.y = acc[i][5]+bsb.y; o1.z = acc[i][6]+bsb.z; o1.w = acc[i][7]+bsb.w;
    *(float4*)crow = o0; *(float4*)(crow + 4) = o1;
  }
}

// ---------------------------------------------------------------------------
// Attention partials: grid (h=16, b=64, c=2), block 128 (thread = m).
// No LDS. K/V row addresses are wave-uniform -> scalar/L1-friendly loads.
// No online max: scores ~N(0,1), exp is safe. Partials combine by addition.
// ---------------------------------------------------------------------------
__global__ __launch_bounds__(128) void attn_part(
    const float* __restrict__ Q, const float* __restrict__ K,
    const float* __restrict__ V, float* __restrict__ Opart,
    float* __restrict__ Lpart)
{
  const int h = blockIdx.x, b = blockIdx.y, c = blockIdx.z;
  const int m = threadIdx.x;
  const int tstart = c ? 257 : 0;
  const int tend   = c ? 513 : 257;

  float q[16];
  {
    const float* qp = Q + ((size_t)(b * 128 + m) << 8) + h * 16;
    #pragma unroll
    for (int i = 0; i < 16; i += 4) {
      const float4 v = *(const float4*)(qp + i);
      q[i] = v.x; q[i+1] = v.y; q[i+2] = v.z; q[i+3] = v.w;
    }
  }

  float l = 0.f, o[16] = {};
  const float* kp = K + ((size_t)(b * 513 + tstart) << 8) + h * 16;
  const float* vp = V + ((size_t)(b * 513 + tstart) << 8) + h * 16;

  for (int t = tstart; t < tend; ++t) {
    const float4 k0 = *(const float4*)(kp);
    const float4 k1 = *(const float4*)(kp + 4);
    const float4 k2 = *(const float4*)(kp + 8);
    const float4 k3 = *(const float4*)(kp + 12);
    const float4 v0 = *(const float4*)(vp);
    const float4 v1 = *(const float4*)(vp + 4);
    const float4 v2 = *(const float4*)(vp + 8);
    const float4 v3 = *(const float4*)(vp + 12);
    float s0 = q[0]*k0.x;  s0 = fmaf(q[1],k0.y,s0);  s0 = fmaf(q[2],k0.z,s0);  s0 = fmaf(q[3],k0.w,s0);
    float s1 = q[4]*k1.x;  s1 = fmaf(q[5],k1.y,s1);  s1 = fmaf(q[6],k1.z,s1);  s1 = fmaf(q[7],k1.w,s1);
    float s2 = q[8]*k2.x;  s2 = fmaf(q[9],k2.y,s2);  s2 = fmaf(q[10],k2.z,s2); s2 = fmaf(q[11],k2.w,s2);
    float s3 = q[12]*k3.x; s3 = fmaf(q[13],k3.y,s3); s3 = fmaf(q[14],k3.z,s3); s3 = fmaf(q[15],k3.w,s3);
    const float e = __expf(((s0 + s1) + (s2 + s3)) * 0.25f);
    l += e;
    o[0]  = fmaf(e, v0.x, o[0]);  o[1]  = fmaf(e, v0.y, o[1]);
    o[2]  = fmaf(e, v0.z, o[2]);  o[3]  = fmaf(e, v0.w, o[3]);
    o[4]  = fmaf(e, v1.x, o[4]);  o[5]  = fmaf(e, v1.y, o[5]);
    o[6]  = fmaf(e, v1.z, o[6]);  o[7]  = fmaf(e, v1.w, o[7]);
    o[8]  = fmaf(e, v2.x, o[8]);  o[9]  = fmaf(e, v2.y, o[9]);
    o[10] = fmaf(e, v2.z, o[10]); o[11] = fmaf(e, v2.w, o[11]);
    o[12] = fmaf(e, v3.x, o[12]); o[13] = fmaf(e, v3.y, o[13]);
    o[14] = fmaf(e, v3.z, o[14]); o[15] = fmaf(e, v3.w, o[15]);
    kp += 256; vp += 256;
  }

  const int idx = (b * 16 + h) * 128 + m;
  float* op = Opart + ((size_t)(c * 131072 + idx) << 4);
  #pragma unroll
  for (int i = 0; i < 16; i += 4) {
    float4 v; v.x = o[i]; v.y = o[i+1]; v.z = o[i+2]; v.w = o[i+3];
    *(float4*)(op + i) = v;
  }
  Lpart[c * 131072 + idx] = l;
}

// Combine 2 T-chunks: o = (o0+o1)/(l0+l1), write out_concat (B,M,H*D).
__global__ __launch_bounds__(256) void attn_combine(
    const float* __restrict__ Opart, const float* __restrict__ Lpart,
    float* __restrict__ OC)
{
  const int gid = blockIdx.x * 256 + threadIdx.x;   // < 131072
  const float* p0 = Opart + ((size_t)gid << 4);
  const float* p1 = Opart + ((size_t)(131072 + gid) << 4);
  const float inv = 1.f / (Lpart[gid] + Lpart[131072 + gid]);
  const int m = gid & 127, bh = gid >> 7, h = bh & 15, b = bh >> 4;
  float* op = OC + ((size_t)(b * 128 + m) << 8) + h * 16;
  #pragma unroll
  for (int i = 0; i < 16; i += 4) {
    const float4 a = *(const float4*)(p0 + i);
    const float4 c = *(const float4*)(p1 + i);
    float4 v;
    v.x = (a.x + c.x) * inv; v.y = (a.y + c.y) * inv;
    v.z = (a.z + c.z) * inv; v.w = (a.w + c.w) * inv;
    *(float4*)(op + i) = v;
  }
}

// ---------------------------------------------------------------------------
// Logits GEMM with fused softmax numerator: writes exp(10*tanh(x/16)+mask-10)
// (mask <= 0 so exponent <= 0 -- no overflow) and writes a DETERMINISTIC
// per-block partial sum (no atomics, no zero-init needed).
// grid (9 t-tiles, 2 m-tiles, 64 b) -> partials[b*18 + bx*2 + by].
// ---------------------------------------------------------------------------
__global__ __launch_bounds__(256) void logits_gemm(
    const float* __restrict__ MH, const float* __restrict__ jobs,
    const float* __restrict__ skip, const float* __restrict__ mask,
    float* __restrict__ out, float* __restrict__ partials)
{
  __shared__ float As[16 * LDT];
  __shared__ float Bs[16 * LDT];
  __shared__ float red[4];
  const int tid = threadIdx.x;
  const int b = blockIdx.z;

  const int m_l = tid >> 2;
  const int kk4 = (tid & 3) << 2;
  const float* arow = MH + ((size_t)(b * 128 + blockIdx.y * 64 + m_l) << 8);

  const int t_g = blockIdx.x * 64 + m_l;
  const float* brow = nullptr;
  if (t_g < 513)
    brow = (t_g == 0) ? skip : (jobs + ((size_t)(b * 512 + t_g - 1) << 8));

  const int tr = tid >> 4, tc = tid & 15;
  float acc[4][4] = {};

  for (int k0 = 0; k0 < 256; k0 += 16) {
    const float4 av = *(const float4*)(arow + k0 + kk4);
    float4 bv = make_float4(0.f, 0.f, 0.f, 0.f);
    if (brow) bv = *(const float4*)(brow + k0 + kk4);
    __syncthreads();
    As[(kk4 + 0) * LDT + m_l] = av.x;
    As[(kk4 + 1) * LDT + m_l] = av.y;
    As[(kk4 + 2) * LDT + m_l] = av.z;
    As[(kk4 + 3) * LDT + m_l] = av.w;
    Bs[(kk4 + 0) * LDT + m_l] = bv.x;
    Bs[(kk4 + 1) * LDT + m_l] = bv.y;
    Bs[(kk4 + 2) * LDT + m_l] = bv.z;
    Bs[(kk4 + 3) * LDT + m_l] = bv.w;
    __syncthreads();
    #pragma unroll
    for (int k = 0; k < 16; ++k) {
      const float4 a  = *(const float4*)&As[k * LDT + (tr << 2)];
      const float4 b4 = *(const float4*)&Bs[k * LDT + (tc << 2)];
      const float aa[4] = {a.x, a.y, a.z, a.w};
      #pragma unroll
      for (int i = 0; i < 4; ++i) {
        acc[i][0] = fmaf(aa[i], b4.x, acc[i][0]);
        acc[i][1] = fmaf(aa[i], b4.y, acc[i][1]);
        acc[i][2] = fmaf(aa[i], b4.z, acc[i][2]);
        acc[i][3] = fmaf(aa[i], b4.w, acc[i][3]);
      }
    }
  }

  float lsum = 0.f;
  #pragma unroll
  for (int i = 0; i < 4; ++i) {
    const int mm = blockIdx.y * 64 + (tr << 2) + i;
    #pragma unroll
    for (int j = 0; j < 4; ++j) {
      const int tt = blockIdx.x * 64 + (tc << 2) + j;
      if (tt < 513) {
        const float lg = 10.f * tanhf(acc[i][j] * 0.0625f)
                       + mask[((size_t)(b * 128 + mm)) * 513 + tt];
        const float e = __expf(lg - 10.f);
        out[(size_t)b * 65664 + (size_t)mm * 513 + tt] = e;
        lsum += e;
      }
    }
  }
  // wave reduce, then LDS reduce across the 4 waves -> one partial per block
  #pragma unroll
  for (int off = 32; off; off >>= 1) lsum += __shfl_xor(lsum, off);
  if ((tid & 63) == 0) red[tid >> 6] = lsum;
  __syncthreads();
  if (tid == 0)
    partials[b * 18 + blockIdx.x * 2 + blockIdx.y] =
        (red[0] + red[1]) + (red[2] + red[3]);
}

// Reduce 18 partials per batch -> 1/sum.
__global__ void sm_inv(const float* __restrict__ partials, float* __restrict__ invb)
{
  const int b = threadIdx.x;
  if (b < 64) {
    float s = 0.f;
    #pragma unroll
    for (int i = 0; i < 18; ++i) s += partials[b * 18 + i];
    invb[b] = 1.f / s;
  }
}

__global__ __launch_bounds__(256) void sm_norm(float* __restrict__ out,
                                               const float* __restrict__ invb)
{
  const int i4 = blockIdx.x * 256 + threadIdx.x;   // float4 index
  if (i4 < 1050624) {
    const int b = i4 / 16416;                      // 65664/4
    float4 v = ((float4*)out)[i4];
    const float s = invb[b];
    v.x *= s; v.y *= s; v.z *= s; v.w *= s;
    ((float4*)out)[i4] = v;
  }
}

// ---------------------------------------------------------------------------
extern "C" void kernel_launch(void* const* d_in, const int* in_sizes, int n_in,
                              void* d_out, int out_size, void* d_ws, size_t ws_size,
                              hipStream_t stream)
{
  const float* machine = (const float*)d_in[0];
  const float* jobs    = (const float*)d_in[1];
  const float* mask    = (const float*)d_in[2];
  const float* Wq      = (const float*)d_in[3];
  const float* Wk      = (const float*)d_in[4];
  const float* Wv      = (const float*)d_in[5];
  const float* Wc      = (const float*)d_in[6];
  const float* bc      = (const float*)d_in[7];
  const float* skip    = (const float*)d_in[8];

  // Workspace layout (floats). Peak = 23,101,440 f = 92.4 MB (same as r1).
  //   [0,        2097152)  Qw, reused as OC after attn_part
  //   [2097152, 10502144)  Kw; first 1216 f reused as partials/invb after attn
  //   [10502144,18907136)  Vw
  //   [18907136,23101440)  Opart (2 x 131072 x 16); first 2097152 f reused as MH
  float* ws       = (float*)d_ws;
  float* Qw       = ws;
  float* Kw       = ws + 2097152;
  float* Vw       = ws + 10502144;
  float* Opart    = ws + 18907136;
  float* MH       = ws + 18907136;     // overlays Opart chunk0 (dead by then)
  float* partials = ws + 2097152;      // overlays Kw (dead after attn_part)
  float* invb     = partials + 1152;
  float* OC       = Qw;                // Q dead after attn_part
  float* out      = (float*)d_out;     // (64, 65664)
  float* Lpart    = out;               // 262,144 f, dead before logits writes

  // Q = machine @ Wq3
  gemm_wide<0,0><<<dim3(2, 128), 256, 0, stream>>>(
      machine, nullptr, nullptr, Wq, nullptr, nullptr, Qw, nullptr);
  // K|V = virtual_jobs @ [Wk | Wv]  (fused, A staged once per 128-wide tile)
  gemm_wide<1,1><<<dim3(4, 513), 256, 0, stream>>>(
      nullptr, jobs, skip, Wk, Wv, nullptr, Kw, Vw);
  // attention partials over 2 T-chunks, then combine
  attn_part<<<dim3(16, 64, 2), 128, 0, stream>>>(Qw, Kw, Vw, Opart, Lpart);
  attn_combine<<<512, 256, 0, stream>>>(Opart, Lpart, OC);
  // mh = out_concat @ Wc + bc
  gemm_wide<0,0><<<dim3(2, 128), 256, 0, stream>>>(
      OC, nullptr, nullptr, Wc, nullptr, bc, MH, nullptr);
  // exp(logits-10) + deterministic per-block partial sums
  logits_gemm<<<dim3(9, 2, 64), 256, 0, stream>>>(MH, jobs, skip, mask, out, partials);
  // 1/sum, then normalize
  sm_inv<<<1, 64, 0, stream>>>(partials, invb);
  sm_norm<<<4104, 256, 0, stream>>>(out, invb);
}

// Round 4
// 386.197 us; speedup vs baseline: 1.4198x; 1.1864x over previous
//
#include <hip/hip_runtime.h>
#include <math.h>

// B=64, M=128, J=512, T=513, E=256, H=16, D=16; out (64, 65664) fp32.

#define LDT 68    // 64-row A-tile LDS leading dim (fp32 gemms)
#define LDB 132   // 128-col B-tile LDS leading dim (fp32 gemms)

typedef __attribute__((ext_vector_type(8))) short bf16x8;   // 8 bf16 = 4 VGPR
typedef __attribute__((ext_vector_type(4))) float f32x4;    // MFMA acc

static __device__ inline unsigned short f2bf(float x) {     // RNE fp32->bf16
  unsigned u = __float_as_uint(x);
  return (unsigned short)((u + 0x7fffu + ((u >> 16) & 1u)) >> 16);
}
static __device__ inline float bf2f(unsigned short h) {
  return __uint_as_float(((unsigned)h) << 16);
}
static __device__ inline unsigned pk(unsigned short a, unsigned short b) {
  return (unsigned)a | ((unsigned)b << 16);
}

// ---------------------------------------------------------------------------
// One-time W split+transpose: Wt[col][k] (bf16 hi/lo), col 0..255 = Wk cols,
// 256..511 = Wv cols. grid 512 blocks x 256 thr (thread = k).
// ---------------------------------------------------------------------------
__global__ void prep_wt(const float* __restrict__ Wk, const float* __restrict__ Wv,
                        unsigned short* __restrict__ Wth, unsigned short* __restrict__ Wtl)
{
  const int c = blockIdx.x, k = threadIdx.x;
  const float x = (c < 256) ? Wk[k * 256 + c] : Wv[k * 256 + (c - 256)];
  const unsigned short h = f2bf(x);
  Wth[c * 256 + k] = h;
  Wtl[c * 256 + k] = f2bf(x - bf2f(h));
}

// ---------------------------------------------------------------------------
// Split-bf16 MFMA GEMM: C(32832 x 512) = vjobs(32832 x 256) @ [Wk|Wv].
// 128x128 tile, 256 thr = 4 waves (2x2, each 64x64 via 4x4 16x16x32 tiles).
// A converted fp32->bf16 hi/lo inline during staging; B pre-split (prep_wt).
// C = Ah*Bh + Ah*Bl + Al*Bh  (error ~2^-17, fp32-grade for this use).
// grid (4 n-tiles, 257 m-tiles); last m-tile clamps rows, guards writes.
// ---------------------------------------------------------------------------
__global__ __launch_bounds__(256) void gemm_kv_mfma(
    const float* __restrict__ jobs, const float* __restrict__ skip,
    const unsigned short* __restrict__ Wth, const unsigned short* __restrict__ Wtl,
    float* __restrict__ Kw, float* __restrict__ Vw)
{
  __shared__ short Ah[128 * 32], Al[128 * 32];   // [row][k] bf16, 8KB each
  __shared__ short Bh[128 * 32], Bl[128 * 32];   // [col][k] bf16
  const int tid = threadIdx.x;
  const int bx = blockIdx.x, by = blockIdx.y;

  // staging map: thread -> (row/col r16 = tid>>1, k-half h16 = (tid&1)*16)
  const int r16 = tid >> 1;
  const int h16 = (tid & 1) << 4;
  int rg = by * 128 + r16; if (rg > 32831) rg = 32831;
  const int bb = rg / 513, tt = rg - bb * 513;
  const float* arow = (tt == 0) ? skip : (jobs + ((size_t)(bb * 512 + tt - 1) << 8));
  const unsigned short* bhrow = Wth + ((size_t)(bx * 128 + r16) << 8);
  const unsigned short* blrow = Wtl + ((size_t)(bx * 128 + r16) << 8);

  // wave tiling
  const int w = tid >> 6, lane = tid & 63;
  const int wr = (w >> 1) << 6, wc = (w & 1) << 6;  // wave origin (rows, cols)
  const int fm = lane & 15, fq = lane >> 4;         // fragment index, quad

  f32x4 acc[4][4] = {};   // [mi][ni]

  for (int kk = 0; kk < 256; kk += 32) {
    // global loads
    const float4 a0 = *(const float4*)(arow + kk + h16);
    const float4 a1 = *(const float4*)(arow + kk + h16 + 4);
    const float4 a2 = *(const float4*)(arow + kk + h16 + 8);
    const float4 a3 = *(const float4*)(arow + kk + h16 + 12);
    const int4 bh0 = *(const int4*)(bhrow + kk + h16);
    const int4 bh1 = *(const int4*)(bhrow + kk + h16 + 8);
    const int4 bl0 = *(const int4*)(blrow + kk + h16);
    const int4 bl1 = *(const int4*)(blrow + kk + h16 + 8);

    // split A into hi/lo bf16
    unsigned short h[16], l[16];
    const float av[16] = {a0.x,a0.y,a0.z,a0.w, a1.x,a1.y,a1.z,a1.w,
                          a2.x,a2.y,a2.z,a2.w, a3.x,a3.y,a3.z,a3.w};
    #pragma unroll
    for (int i = 0; i < 16; ++i) {
      h[i] = f2bf(av[i]);
      l[i] = f2bf(av[i] - bf2f(h[i]));
    }

    __syncthreads();   // previous iter's fragment reads done
    const int so = r16 * 32 + h16;
    ((int4*)&Ah[so])[0] = make_int4(pk(h[0],h[1]), pk(h[2],h[3]), pk(h[4],h[5]), pk(h[6],h[7]));
    ((int4*)&Ah[so])[1] = make_int4(pk(h[8],h[9]), pk(h[10],h[11]), pk(h[12],h[13]), pk(h[14],h[15]));
    ((int4*)&Al[so])[0] = make_int4(pk(l[0],l[1]), pk(l[2],l[3]), pk(l[4],l[5]), pk(l[6],l[7]));
    ((int4*)&Al[so])[1] = make_int4(pk(l[8],l[9]), pk(l[10],l[11]), pk(l[12],l[13]), pk(l[14],l[15]));
    *(int4*)&Bh[so] = bh0; *(int4*)&Bh[so + 8] = bh1;
    *(int4*)&Bl[so] = bl0; *(int4*)&Bl[so + 8] = bl1;
    __syncthreads();

    // fragments: lane holds [m/n = fm][k = fq*8 + j]
    bf16x8 afh[4], afl[4], bfh[4], bfl[4];
    #pragma unroll
    for (int i = 0; i < 4; ++i) {
      const int ai = (wr + i * 16 + fm) * 32 + fq * 8;
      const int bi = (wc + i * 16 + fm) * 32 + fq * 8;
      afh[i] = *(const bf16x8*)&Ah[ai];
      afl[i] = *(const bf16x8*)&Al[ai];
      bfh[i] = *(const bf16x8*)&Bh[bi];
      bfl[i] = *(const bf16x8*)&Bl[bi];
    }
    #pragma unroll
    for (int mi = 0; mi < 4; ++mi)
      #pragma unroll
      for (int ni = 0; ni < 4; ++ni) {
        acc[mi][ni] = __builtin_amdgcn_mfma_f32_16x16x32_bf16(afh[mi], bfl[ni], acc[mi][ni], 0, 0, 0);
        acc[mi][ni] = __builtin_amdgcn_mfma_f32_16x16x32_bf16(afl[mi], bfh[ni], acc[mi][ni], 0, 0, 0);
        acc[mi][ni] = __builtin_amdgcn_mfma_f32_16x16x32_bf16(afh[mi], bfh[ni], acc[mi][ni], 0, 0, 0);
      }
  }

  // epilogue: C/D layout col = lane&15, row = fq*4 + reg
  float* Cb = (bx < 2) ? Kw : Vw;
  const int cb = ((bx & 1) << 7) + wc;
  #pragma unroll
  for (int mi = 0; mi < 4; ++mi) {
    #pragma unroll
    for (int r = 0; r < 4; ++r) {
      const int row = by * 128 + wr + mi * 16 + fq * 4 + r;
      if (row < 32832) {
        float* crow = Cb + (size_t)row * 256 + cb;
        #pragma unroll
        for (int ni = 0; ni < 4; ++ni)
          crow[ni * 16 + fm] = acc[mi][ni][r];
      }
    }
  }
}

// ---------------------------------------------------------------------------
// Wide tiled fp32 GEMM (Q and Wc projections): C[rows x 256] = A @ W (+bias)
// ---------------------------------------------------------------------------
template<int MODE>
__global__ __launch_bounds__(256) void gemm_wide(
    const float* __restrict__ A, const float* __restrict__ jobs,
    const float* __restrict__ skip, const float* __restrict__ W1,
    const float* __restrict__ bias, float* __restrict__ C1)
{
  __shared__ float As[16 * LDT];
  __shared__ float Bs[16 * LDB];
  const int tid = threadIdx.x;
  const int bx = blockIdx.x, by = blockIdx.y;

  const float* W = W1; float* C = C1; const int col0 = bx * 128;

  const int a_row = tid >> 2;
  const int a_k4  = (tid & 3) << 2;
  const int row = by * 64 + a_row;
  const float* arow;
  if (MODE == 0) {
    arow = A + ((size_t)row << 8);
  } else {
    const int bb = row / 513;
    const int t  = row - bb * 513;
    arow = (t == 0) ? skip : (jobs + ((size_t)(bb * 512 + t - 1) << 8));
  }

  const int b_k  = tid >> 4;
  const int b_c8 = (tid & 15) << 3;

  const int tr = tid >> 4, tc = tid & 15;
  float acc[4][8] = {};

  for (int k0 = 0; k0 < 256; k0 += 16) {
    const float4 av  = *(const float4*)(arow + k0 + a_k4);
    const float4 bv0 = *(const float4*)(W + ((size_t)(k0 + b_k) << 8) + col0 + b_c8);
    const float4 bv1 = *(const float4*)(W + ((size_t)(k0 + b_k) << 8) + col0 + b_c8 + 4);
    __syncthreads();
    As[(a_k4 + 0) * LDT + a_row] = av.x;
    As[(a_k4 + 1) * LDT + a_row] = av.y;
    As[(a_k4 + 2) * LDT + a_row] = av.z;
    As[(a_k4 + 3) * LDT + a_row] = av.w;
    *(float4*)&Bs[b_k * LDB + b_c8]     = bv0;
    *(float4*)&Bs[b_k * LDB + b_c8 + 4] = bv1;
    __syncthreads();
    #pragma unroll
    for (int k = 0; k < 16; ++k) {
      const float4 a  = *(const float4*)&As[k * LDT + (tr << 2)];
      const float4 b0 = *(const float4*)&Bs[k * LDB + (tc << 3)];
      const float4 b1 = *(const float4*)&Bs[k * LDB + (tc << 3) + 4];
      const float aa[4] = {a.x, a.y, a.z, a.w};
      #pragma unroll
      for (int i = 0; i < 4; ++i) {
        acc[i][0] = fmaf(aa[i], b0.x, acc[i][0]);
        acc[i][1] = fmaf(aa[i], b0.y, acc[i][1]);
        acc[i][2] = fmaf(aa[i], b0.z, acc[i][2]);
        acc[i][3] = fmaf(aa[i], b0.w, acc[i][3]);
        acc[i][4] = fmaf(aa[i], b1.x, acc[i][4]);
        acc[i][5] = fmaf(aa[i], b1.y, acc[i][5]);
        acc[i][6] = fmaf(aa[i], b1.z, acc[i][6]);
        acc[i][7] = fmaf(aa[i], b1.w, acc[i][7]);
      }
    }
  }

  const int oc = col0 + (tc << 3);
  float4 bsa = make_float4(0.f,0.f,0.f,0.f), bsb = make_float4(0.f,0.f,0.f,0.f);
  if (bias) { bsa = *(const float4*)(bias + oc); bsb = *(const float4*)(bias + oc + 4); }
  #pragma unroll
  for (int i = 0; i < 4; ++i) {
    float* crow = C + ((size_t)(by * 64 + (tr << 2) + i) << 8) + oc;
    float4 o0, o1;
    o0.x = acc[i][0]+bsa.x; o0.y = acc[i][1]+bsa.y; o0.z = acc[i][2]+bsa.z; o0.w = acc[i][3]+bsa.w;
    o1.x = acc[i][4]+bsb.x; o1.y = acc[i][5]+bsb.y; o1.z = acc[i][6]+bsb.z; o1.w = acc[i][7]+bsb.w;
    *(float4*)crow = o0; *(float4*)(crow + 4) = o1;
  }
}

// ---------------------------------------------------------------------------
// Attention partials: grid (h=16, b=64, c=2), block 128 (thread = m).
// ---------------------------------------------------------------------------
__global__ __launch_bounds__(128) void attn_part(
    const float* __restrict__ Q, const float* __restrict__ K,
    const float* __restrict__ V, float* __restrict__ Opart,
    float* __restrict__ Lpart)
{
  const int h = blockIdx.x, b = blockIdx.y, c = blockIdx.z;
  const int m = threadIdx.x;
  const int tstart = c ? 257 : 0;
  const int tend   = c ? 513 : 257;

  float q[16];
  {
    const float* qp = Q + ((size_t)(b * 128 + m) << 8) + h * 16;
    #pragma unroll
    for (int i = 0; i < 16; i += 4) {
      const float4 v = *(const float4*)(qp + i);
      q[i] = v.x; q[i+1] = v.y; q[i+2] = v.z; q[i+3] = v.w;
    }
  }

  float l = 0.f, o[16] = {};
  const float* kp = K + ((size_t)(b * 513 + tstart) << 8) + h * 16;
  const float* vp = V + ((size_t)(b * 513 + tstart) << 8) + h * 16;

  for (int t = tstart; t < tend; ++t) {
    const float4 k0 = *(const float4*)(kp);
    const float4 k1 = *(const float4*)(kp + 4);
    const float4 k2 = *(const float4*)(kp + 8);
    const float4 k3 = *(const float4*)(kp + 12);
    const float4 v0 = *(const float4*)(vp);
    const float4 v1 = *(const float4*)(vp + 4);
    const float4 v2 = *(const float4*)(vp + 8);
    const float4 v3 = *(const float4*)(vp + 12);
    float s0 = q[0]*k0.x;  s0 = fmaf(q[1],k0.y,s0);  s0 = fmaf(q[2],k0.z,s0);  s0 = fmaf(q[3],k0.w,s0);
    float s1 = q[4]*k1.x;  s1 = fmaf(q[5],k1.y,s1);  s1 = fmaf(q[6],k1.z,s1);  s1 = fmaf(q[7],k1.w,s1);
    float s2 = q[8]*k2.x;  s2 = fmaf(q[9],k2.y,s2);  s2 = fmaf(q[10],k2.z,s2); s2 = fmaf(q[11],k2.w,s2);
    float s3 = q[12]*k3.x; s3 = fmaf(q[13],k3.y,s3); s3 = fmaf(q[14],k3.z,s3); s3 = fmaf(q[15],k3.w,s3);
    const float e = __expf(((s0 + s1) + (s2 + s3)) * 0.25f);
    l += e;
    o[0]  = fmaf(e, v0.x, o[0]);  o[1]  = fmaf(e, v0.y, o[1]);
    o[2]  = fmaf(e, v0.z, o[2]);  o[3]  = fmaf(e, v0.w, o[3]);
    o[4]  = fmaf(e, v1.x, o[4]);  o[5]  = fmaf(e, v1.y, o[5]);
    o[6]  = fmaf(e, v1.z, o[6]);  o[7]  = fmaf(e, v1.w, o[7]);
    o[8]  = fmaf(e, v2.x, o[8]);  o[9]  = fmaf(e, v2.y, o[9]);
    o[10] = fmaf(e, v2.z, o[10]); o[11] = fmaf(e, v2.w, o[11]);
    o[12] = fmaf(e, v3.x, o[12]); o[13] = fmaf(e, v3.y, o[13]);
    o[14] = fmaf(e, v3.z, o[14]); o[15] = fmaf(e, v3.w, o[15]);
    kp += 256; vp += 256;
  }

  const int idx = (b * 16 + h) * 128 + m;
  float* op = Opart + ((size_t)(c * 131072 + idx) << 4);
  #pragma unroll
  for (int i = 0; i < 16; i += 4) {
    float4 v; v.x = o[i]; v.y = o[i+1]; v.z = o[i+2]; v.w = o[i+3];
    *(float4*)(op + i) = v;
  }
  Lpart[c * 131072 + idx] = l;
}

// Combine 2 T-chunks: o = (o0+o1)/(l0+l1), write out_concat (B,M,H*D).
__global__ __launch_bounds__(256) void attn_combine(
    const float* __restrict__ Opart, const float* __restrict__ Lpart,
    float* __restrict__ OC)
{
  const int gid = blockIdx.x * 256 + threadIdx.x;   // < 131072
  const float* p0 = Opart + ((size_t)gid << 4);
  const float* p1 = Opart + ((size_t)(131072 + gid) << 4);
  const float inv = 1.f / (Lpart[gid] + Lpart[131072 + gid]);
  const int m = gid & 127, bh = gid >> 7, h = bh & 15, b = bh >> 4;
  float* op = OC + ((size_t)(b * 128 + m) << 8) + h * 16;
  #pragma unroll
  for (int i = 0; i < 16; i += 4) {
    const float4 a = *(const float4*)(p0 + i);
    const float4 c = *(const float4*)(p1 + i);
    float4 v;
    v.x = (a.x + c.x) * inv; v.y = (a.y + c.y) * inv;
    v.z = (a.z + c.z) * inv; v.w = (a.w + c.w) * inv;
    *(float4*)(op + i) = v;
  }
}

// ---------------------------------------------------------------------------
// Logits GEMM, fused exp(10*tanh(x/16)+mask-10) + deterministic partials.
// ---------------------------------------------------------------------------
__global__ __launch_bounds__(256) void logits_gemm(
    const float* __restrict__ MH, const float* __restrict__ jobs,
    const float* __restrict__ skip, const float* __restrict__ mask,
    float* __restrict__ out, float* __restrict__ partials)
{
  __shared__ float As[16 * LDT];
  __shared__ float Bs[16 * LDT];
  __shared__ float red[4];
  const int tid = threadIdx.x;
  const int b = blockIdx.z;

  const int m_l = tid >> 2;
  const int kk4 = (tid & 3) << 2;
  const float* arow = MH + ((size_t)(b * 128 + blockIdx.y * 64 + m_l) << 8);

  const int t_g = blockIdx.x * 64 + m_l;
  const float* brow = nullptr;
  if (t_g < 513)
    brow = (t_g == 0) ? skip : (jobs + ((size_t)(b * 512 + t_g - 1) << 8));

  const int tr = tid >> 4, tc = tid & 15;
  float acc[4][4] = {};

  for (int k0 = 0; k0 < 256; k0 += 16) {
    const float4 av = *(const float4*)(arow + k0 + kk4);
    float4 bv = make_float4(0.f, 0.f, 0.f, 0.f);
    if (brow) bv = *(const float4*)(brow + k0 + kk4);
    __syncthreads();
    As[(kk4 + 0) * LDT + m_l] = av.x;
    As[(kk4 + 1) * LDT + m_l] = av.y;
    As[(kk4 + 2) * LDT + m_l] = av.z;
    As[(kk4 + 3) * LDT + m_l] = av.w;
    Bs[(kk4 + 0) * LDT + m_l] = bv.x;
    Bs[(kk4 + 1) * LDT + m_l] = bv.y;
    Bs[(kk4 + 2) * LDT + m_l] = bv.z;
    Bs[(kk4 + 3) * LDT + m_l] = bv.w;
    __syncthreads();
    #pragma unroll
    for (int k = 0; k < 16; ++k) {
      const float4 a  = *(const float4*)&As[k * LDT + (tr << 2)];
      const float4 b4 = *(const float4*)&Bs[k * LDT + (tc << 2)];
      const float aa[4] = {a.x, a.y, a.z, a.w};
      #pragma unroll
      for (int i = 0; i < 4; ++i) {
        acc[i][0] = fmaf(aa[i], b4.x, acc[i][0]);
        acc[i][1] = fmaf(aa[i], b4.y, acc[i][1]);
        acc[i][2] = fmaf(aa[i], b4.z, acc[i][2]);
        acc[i][3] = fmaf(aa[i], b4.w, acc[i][3]);
      }
    }
  }

  float lsum = 0.f;
  #pragma unroll
  for (int i = 0; i < 4; ++i) {
    const int mm = blockIdx.y * 64 + (tr << 2) + i;
    #pragma unroll
    for (int j = 0; j < 4; ++j) {
      const int tt = blockIdx.x * 64 + (tc << 2) + j;
      if (tt < 513) {
        const float lg = 10.f * tanhf(acc[i][j] * 0.0625f)
                       + mask[((size_t)(b * 128 + mm)) * 513 + tt];
        const float e = __expf(lg - 10.f);
        out[(size_t)b * 65664 + (size_t)mm * 513 + tt] = e;
        lsum += e;
      }
    }
  }
  #pragma unroll
  for (int off = 32; off; off >>= 1) lsum += __shfl_xor(lsum, off);
  if ((tid & 63) == 0) red[tid >> 6] = lsum;
  __syncthreads();
  if (tid == 0)
    partials[b * 18 + blockIdx.x * 2 + blockIdx.y] =
        (red[0] + red[1]) + (red[2] + red[3]);
}

__global__ void sm_inv(const float* __restrict__ partials, float* __restrict__ invb)
{
  const int b = threadIdx.x;
  if (b < 64) {
    float s = 0.f;
    #pragma unroll
    for (int i = 0; i < 18; ++i) s += partials[b * 18 + i];
    invb[b] = 1.f / s;
  }
}

__global__ __launch_bounds__(256) void sm_norm(float* __restrict__ out,
                                               const float* __restrict__ invb)
{
  const int i4 = blockIdx.x * 256 + threadIdx.x;
  if (i4 < 1050624) {
    const int b = i4 / 16416;
    float4 v = ((float4*)out)[i4];
    const float s = invb[b];
    v.x *= s; v.y *= s; v.z *= s; v.w *= s;
    ((float4*)out)[i4] = v;
  }
}

// ---------------------------------------------------------------------------
extern "C" void kernel_launch(void* const* d_in, const int* in_sizes, int n_in,
                              void* d_out, int out_size, void* d_ws, size_t ws_size,
                              hipStream_t stream)
{
  const float* machine = (const float*)d_in[0];
  const float* jobs    = (const float*)d_in[1];
  const float* mask    = (const float*)d_in[2];
  const float* Wq      = (const float*)d_in[3];
  const float* Wk      = (const float*)d_in[4];
  const float* Wv      = (const float*)d_in[5];
  const float* Wc      = (const float*)d_in[6];
  const float* bc      = (const float*)d_in[7];
  const float* skip    = (const float*)d_in[8];

  // Workspace (floats). Peak 23,101,440 f = 92.4 MB (same as r1/r3).
  //   [0,        2097152)  Qw -> OC after attn
  //   [2097152, 10502144)  Kw; first 1216 f reused as partials/invb after attn
  //   [10502144,18907136)  Vw
  //   [18907136,23101440)  Wt (bf16, 131072 f) -> Opart -> MH (overlapping lifetimes)
  float* ws       = (float*)d_ws;
  float* Qw       = ws;
  float* Kw       = ws + 2097152;
  float* Vw       = ws + 10502144;
  unsigned short* Wth = (unsigned short*)(ws + 18907136);  // dead before Opart written
  unsigned short* Wtl = Wth + 131072;
  float* Opart    = ws + 18907136;
  float* MH       = ws + 18907136;     // overlays Opart chunk0 (dead by then)
  float* partials = ws + 2097152;      // overlays Kw (dead after attn_part)
  float* invb     = partials + 1152;
  float* OC       = Qw;
  float* out      = (float*)d_out;
  float* Lpart    = out;               // dead before logits writes

  // Q = machine @ Wq3 (fp32)
  gemm_wide<0><<<dim3(2, 128), 256, 0, stream>>>(
      machine, nullptr, nullptr, Wq, nullptr, Qw);
  // W split/transpose, then K|V = vjobs @ [Wk|Wv] via split-bf16 MFMA
  prep_wt<<<512, 256, 0, stream>>>(Wk, Wv, Wth, Wtl);
  gemm_kv_mfma<<<dim3(4, 257), 256, 0, stream>>>(jobs, skip, Wth, Wtl, Kw, Vw);
  // attention partials + combine
  attn_part<<<dim3(16, 64, 2), 128, 0, stream>>>(Qw, Kw, Vw, Opart, Lpart);
  attn_combine<<<512, 256, 0, stream>>>(Opart, Lpart, OC);
  // mh = out_concat @ Wc + bc (fp32)
  gemm_wide<0><<<dim3(2, 128), 256, 0, stream>>>(
      OC, nullptr, nullptr, Wc, bc, MH);
  // exp(logits-10) + partials
  logits_gemm<<<dim3(9, 2, 64), 256, 0, stream>>>(MH, jobs, skip, mask, out, partials);
  sm_inv<<<1, 64, 0, stream>>>(partials, invb);
  sm_norm<<<4104, 256, 0, stream>>>(out, invb);
}